// Round 1
// baseline (182.183 us; speedup 1.0000x reference)
//
#include <hip/hip_runtime.h>
#include <hip/hip_bf16.h>

#define BX 64
#define BY 4

// ---------------------------------------------------------------------------
// Per-level bilateral-filter MSE loss.
// Each thread: one output pixel. 5x5 zero-padded neighborhood of fake/hdr from
// LDS tile; 25 r_weight reads (coalesced along x). Result reduced to one
// atomicAdd(double) per block, pre-scaled by pyr_w / (B*S*S).
// ---------------------------------------------------------------------------
__global__ __launch_bounds__(256) void level_loss_kernel(
    const float* __restrict__ fake, const float* __restrict__ hdr,
    const float* __restrict__ window, const float* __restrict__ rw,
    double* __restrict__ acc, int B, int S, float scale)
{
    __shared__ float sf[BY + 4][BX + 4];
    __shared__ float sh[BY + 4][BX + 4];
    __shared__ float swin[25];
    __shared__ float wred[4];

    const int tx = threadIdx.x, ty = threadIdx.y;
    const int tid = ty * BX + tx;
    if (tid < 25) swin[tid] = window[tid];

    const int bx0 = blockIdx.x * BX;
    const int by0 = blockIdx.y * BY;
    const int b   = blockIdx.z;

    const float* F  = fake + (size_t)b * S * S;
    const float* Hp = hdr  + (size_t)b * S * S;

    // Load (BY+4) x (BX+4) halo tile, zero-padded outside the image.
    for (int i = tid; i < (BY + 4) * (BX + 4); i += BX * BY) {
        const int r = i / (BX + 4), c = i % (BX + 4);
        const int y = by0 + r - 2, x = bx0 + c - 2;
        float fv = 0.f, hv = 0.f;
        if ((unsigned)y < (unsigned)S && (unsigned)x < (unsigned)S) {
            const size_t idx = (size_t)y * S + x;
            fv = F[idx]; hv = Hp[idx];
        }
        sf[r][c] = fv; sh[r][c] = hv;
    }
    __syncthreads();

    const int x = bx0 + tx, y = by0 + ty;
    const float* rwp = rw + (size_t)b * 25 * S * S + (size_t)y * S + x;
    const size_t ks = (size_t)S * S;

    float wsum = 0.f, fsum = 0.f, hsum = 0.f;
#pragma unroll
    for (int di = 0; di < 5; ++di) {
#pragma unroll
        for (int dj = 0; dj < 5; ++dj) {
            const int k = di * 5 + dj;
            const float wm = swin[k] * rwp[(size_t)k * ks];
            wsum += wm;
            fsum = fmaf(wm, sf[ty + di][tx + dj], fsum);
            hsum = fmaf(wm, sh[ty + di][tx + dj], hsum);
        }
    }
    const float d = (fsum - hsum) / wsum;
    float v = d * d;

    // wave (64-lane) reduce, then cross-wave via LDS
#pragma unroll
    for (int off = 32; off > 0; off >>= 1) v += __shfl_down(v, off, 64);
    if ((tid & 63) == 0) wred[tid >> 6] = v;
    __syncthreads();
    if (tid == 0) {
        const float s = wred[0] + wred[1] + wred[2] + wred[3];
        atomicAdd(acc, (double)s * (double)scale);
    }
}

// ---------------------------------------------------------------------------
// Bicubic /2 downsample (torch bicubic a=-0.75, scale 0.5, align_corners=False
// -> fixed taps at src 2i-1..2i+2, edge-clamped). Handles two images (fake &
// hdr) in one launch via blockIdx.z in [0, 2B).
// ---------------------------------------------------------------------------
__global__ __launch_bounds__(256) void down2_kernel(
    const float* __restrict__ inA, float* __restrict__ outA,
    const float* __restrict__ inB, float* __restrict__ outB,
    int B, int Hin)
{
    const int Win = Hin;
    const int Ho = Hin >> 1, Wo = Win >> 1;
    const int x = blockIdx.x * blockDim.x + threadIdx.x;
    const int y = blockIdx.y * blockDim.y + threadIdx.y;
    const int z = blockIdx.z;
    if (x >= Wo || y >= Ho) return;

    const float* in = (z < B) ? inA : inB;
    float* out      = (z < B) ? outA : outB;
    const int b     = (z < B) ? z : z - B;
    const float* src = in + (size_t)b * Hin * Win;

    const float wt0 = -0.09375f, wt1 = 0.59375f;
    int ys[4], xs[4];
#pragma unroll
    for (int k = 0; k < 4; ++k) {
        int yy = 2 * y + k - 1; ys[k] = min(max(yy, 0), Hin - 1);
        int xx = 2 * x + k - 1; xs[k] = min(max(xx, 0), Win - 1);
    }
    float a = 0.f;
#pragma unroll
    for (int ky = 0; ky < 4; ++ky) {
        const float* r = src + (size_t)ys[ky] * Win;
        const float ra = wt0 * (r[xs[0]] + r[xs[3]]) + wt1 * (r[xs[1]] + r[xs[2]]);
        const float w = (ky == 0 || ky == 3) ? wt0 : wt1;
        a = fmaf(w, ra, a);
    }
    out[((size_t)b * Ho + y) * Wo + x] = a;
}

__global__ void finalize_kernel(const double* __restrict__ acc, float* __restrict__ out)
{
    if (threadIdx.x == 0) out[0] = (float)(*acc);
}

extern "C" void kernel_launch(void* const* d_in, const int* in_sizes, int n_in,
                              void* d_out, int out_size, void* d_ws, size_t ws_size,
                              hipStream_t stream)
{
    const float* fake   = (const float*)d_in[0];
    const float* hdr    = (const float*)d_in[1];
    const float* window = (const float*)d_in[2];
    const float* rw0    = (const float*)d_in[3];
    const float* rw1    = (const float*)d_in[4];
    const float* rw2    = (const float*)d_in[5];
    const float* rw3    = (const float*)d_in[6];
    float* out = (float*)d_out;

    const int B = 8;

    char* ws = (char*)d_ws;
    double* acc = (double*)ws;                  // 8 bytes @ 0
    float* f1 = (float*)(ws + 256);
    const size_t n1 = (size_t)B * 256 * 256;
    float* h1 = f1 + n1;
    float* f2 = h1 + n1;
    const size_t n2 = (size_t)B * 128 * 128;
    float* h2 = f2 + n2;
    float* f3 = h2 + n2;
    const size_t n3 = (size_t)B * 64 * 64;
    float* h3 = f3 + n3;

    hipMemsetAsync(acc, 0, sizeof(double), stream);

    const dim3 blk(BX, BY);

    // level 0 (uses original inputs; independent of downsamples)
    level_loss_kernel<<<dim3(512 / BX, 512 / BY, B), blk, 0, stream>>>(
        fake, hdr, window, rw0, acc, B, 512, 1.0f / (8.f * 512.f * 512.f));

    // 512 -> 256
    down2_kernel<<<dim3(256 / BX, 256 / BY, 2 * B), blk, 0, stream>>>(fake, f1, hdr, h1, B, 512);
    level_loss_kernel<<<dim3(256 / BX, 256 / BY, B), blk, 0, stream>>>(
        f1, h1, window, rw1, acc, B, 256, 0.5f / (8.f * 256.f * 256.f));

    // 256 -> 128
    down2_kernel<<<dim3(128 / BX, 128 / BY, 2 * B), blk, 0, stream>>>(f1, f2, h1, h2, B, 256);
    level_loss_kernel<<<dim3(128 / BX, 128 / BY, B), blk, 0, stream>>>(
        f2, h2, window, rw2, acc, B, 128, 0.25f / (8.f * 128.f * 128.f));

    // 128 -> 64
    down2_kernel<<<dim3(64 / BX, 64 / BY, 2 * B), blk, 0, stream>>>(f2, f3, h2, h3, B, 128);
    level_loss_kernel<<<dim3(64 / BX, 64 / BY, B), blk, 0, stream>>>(
        f3, h3, window, rw3, acc, B, 64, 0.125f / (8.f * 64.f * 64.f));

    finalize_kernel<<<1, 64, 0, stream>>>(acc, out);
}

// Round 2
// 85.954 us; speedup vs baseline: 2.1195x; 2.1195x over previous
//
#include <hip/hip_runtime.h>
#include <hip/hip_bf16.h>

#define BX 64
#define BY 4
#define NSLOT 256
#define SLOT_STRIDE 16  // doubles; 128 B between slots -> no cacheline sharing

// ---------------------------------------------------------------------------
// Per-level bilateral-filter MSE loss.
// Each thread: one output pixel. 5x5 zero-padded neighborhood of fake/hdr from
// LDS tile; 25 r_weight reads (coalesced along x). Block partial goes to one
// of 256 cacheline-spread double slots (avoids same-address atomic
// serialization, which was the R1 bottleneck: 8192 serialized RMWs ~= 121us).
// ---------------------------------------------------------------------------
__global__ __launch_bounds__(256) void level_loss_kernel(
    const float* __restrict__ fake, const float* __restrict__ hdr,
    const float* __restrict__ window, const float* __restrict__ rw,
    double* __restrict__ acc, int B, int S, float scale)
{
    __shared__ float sf[BY + 4][BX + 4];
    __shared__ float sh[BY + 4][BX + 4];
    __shared__ float swin[25];
    __shared__ float wred[4];

    const int tx = threadIdx.x, ty = threadIdx.y;
    const int tid = ty * BX + tx;
    if (tid < 25) swin[tid] = window[tid];

    const int bx0 = blockIdx.x * BX;
    const int by0 = blockIdx.y * BY;
    const int b   = blockIdx.z;

    const float* F  = fake + (size_t)b * S * S;
    const float* Hp = hdr  + (size_t)b * S * S;

    // Load (BY+4) x (BX+4) halo tile, zero-padded outside the image.
    for (int i = tid; i < (BY + 4) * (BX + 4); i += BX * BY) {
        const int r = i / (BX + 4), c = i % (BX + 4);
        const int y = by0 + r - 2, x = bx0 + c - 2;
        float fv = 0.f, hv = 0.f;
        if ((unsigned)y < (unsigned)S && (unsigned)x < (unsigned)S) {
            const size_t idx = (size_t)y * S + x;
            fv = F[idx]; hv = Hp[idx];
        }
        sf[r][c] = fv; sh[r][c] = hv;
    }
    __syncthreads();

    const int x = bx0 + tx, y = by0 + ty;
    const float* rwp = rw + (size_t)b * 25 * S * S + (size_t)y * S + x;
    const size_t ks = (size_t)S * S;

    float wsum = 0.f, fsum = 0.f, hsum = 0.f;
#pragma unroll
    for (int di = 0; di < 5; ++di) {
#pragma unroll
        for (int dj = 0; dj < 5; ++dj) {
            const int k = di * 5 + dj;
            const float wm = swin[k] * rwp[(size_t)k * ks];
            wsum += wm;
            fsum = fmaf(wm, sf[ty + di][tx + dj], fsum);
            hsum = fmaf(wm, sh[ty + di][tx + dj], hsum);
        }
    }
    const float d = (fsum - hsum) / wsum;
    float v = d * d;

    // wave (64-lane) reduce, then cross-wave via LDS
#pragma unroll
    for (int off = 32; off > 0; off >>= 1) v += __shfl_down(v, off, 64);
    if ((tid & 63) == 0) wred[tid >> 6] = v;
    __syncthreads();
    if (tid == 0) {
        const float s = wred[0] + wred[1] + wred[2] + wred[3];
        const unsigned lin = blockIdx.x + gridDim.x * (blockIdx.y + gridDim.y * blockIdx.z);
        atomicAdd(&acc[(lin & (NSLOT - 1)) * SLOT_STRIDE], (double)s * (double)scale);
    }
}

// ---------------------------------------------------------------------------
// Bicubic /2 downsample (torch bicubic a=-0.75, scale 0.5, align_corners=False
// -> fixed taps at src 2i-1..2i+2, edge-clamped). Handles two images (fake &
// hdr) in one launch via blockIdx.z in [0, 2B).
// ---------------------------------------------------------------------------
__global__ __launch_bounds__(256) void down2_kernel(
    const float* __restrict__ inA, float* __restrict__ outA,
    const float* __restrict__ inB, float* __restrict__ outB,
    int B, int Hin)
{
    const int Win = Hin;
    const int Ho = Hin >> 1, Wo = Win >> 1;
    const int x = blockIdx.x * blockDim.x + threadIdx.x;
    const int y = blockIdx.y * blockDim.y + threadIdx.y;
    const int z = blockIdx.z;
    if (x >= Wo || y >= Ho) return;

    const float* in = (z < B) ? inA : inB;
    float* out      = (z < B) ? outA : outB;
    const int b     = (z < B) ? z : z - B;
    const float* src = in + (size_t)b * Hin * Win;

    const float wt0 = -0.09375f, wt1 = 0.59375f;
    int ys[4], xs[4];
#pragma unroll
    for (int k = 0; k < 4; ++k) {
        int yy = 2 * y + k - 1; ys[k] = min(max(yy, 0), Hin - 1);
        int xx = 2 * x + k - 1; xs[k] = min(max(xx, 0), Win - 1);
    }
    float a = 0.f;
#pragma unroll
    for (int ky = 0; ky < 4; ++ky) {
        const float* r = src + (size_t)ys[ky] * Win;
        const float ra = wt0 * (r[xs[0]] + r[xs[3]]) + wt1 * (r[xs[1]] + r[xs[2]]);
        const float w = (ky == 0 || ky == 3) ? wt0 : wt1;
        a = fmaf(w, ra, a);
    }
    out[((size_t)b * Ho + y) * Wo + x] = a;
}

__global__ void finalize_kernel(const double* __restrict__ acc, float* __restrict__ out)
{
    const int t = threadIdx.x;  // 64 threads
    double s = 0.0;
#pragma unroll
    for (int i = 0; i < NSLOT / 64; ++i)
        s += acc[(t + i * 64) * SLOT_STRIDE];
#pragma unroll
    for (int off = 32; off > 0; off >>= 1)
        s += __shfl_down(s, off, 64);
    if (t == 0) out[0] = (float)s;
}

extern "C" void kernel_launch(void* const* d_in, const int* in_sizes, int n_in,
                              void* d_out, int out_size, void* d_ws, size_t ws_size,
                              hipStream_t stream)
{
    const float* fake   = (const float*)d_in[0];
    const float* hdr    = (const float*)d_in[1];
    const float* window = (const float*)d_in[2];
    const float* rw0    = (const float*)d_in[3];
    const float* rw1    = (const float*)d_in[4];
    const float* rw2    = (const float*)d_in[5];
    const float* rw3    = (const float*)d_in[6];
    float* out = (float*)d_out;

    const int B = 8;

    char* ws = (char*)d_ws;
    double* acc = (double*)ws;                  // NSLOT*SLOT_STRIDE doubles = 32 KB
    float* f1 = (float*)(ws + NSLOT * SLOT_STRIDE * sizeof(double));
    const size_t n1 = (size_t)B * 256 * 256;
    float* h1 = f1 + n1;
    float* f2 = h1 + n1;
    const size_t n2 = (size_t)B * 128 * 128;
    float* h2 = f2 + n2;
    float* f3 = h2 + n2;
    const size_t n3 = (size_t)B * 64 * 64;
    float* h3 = f3 + n3;

    hipMemsetAsync(acc, 0, NSLOT * SLOT_STRIDE * sizeof(double), stream);

    const dim3 blk(BX, BY);

    // level 0 (uses original inputs; independent of downsamples)
    level_loss_kernel<<<dim3(512 / BX, 512 / BY, B), blk, 0, stream>>>(
        fake, hdr, window, rw0, acc, B, 512, 1.0f / (8.f * 512.f * 512.f));

    // 512 -> 256
    down2_kernel<<<dim3(256 / BX, 256 / BY, 2 * B), blk, 0, stream>>>(fake, f1, hdr, h1, B, 512);
    level_loss_kernel<<<dim3(256 / BX, 256 / BY, B), blk, 0, stream>>>(
        f1, h1, window, rw1, acc, B, 256, 0.5f / (8.f * 256.f * 256.f));

    // 256 -> 128
    down2_kernel<<<dim3(128 / BX, 128 / BY, 2 * B), blk, 0, stream>>>(f1, f2, h1, h2, B, 256);
    level_loss_kernel<<<dim3(128 / BX, 128 / BY, B), blk, 0, stream>>>(
        f2, h2, window, rw2, acc, B, 128, 0.25f / (8.f * 128.f * 128.f));

    // 128 -> 64
    down2_kernel<<<dim3(64 / BX, 64 / BY, 2 * B), blk, 0, stream>>>(f2, f3, h2, h3, B, 128);
    level_loss_kernel<<<dim3(64 / BX, 64 / BY, B), blk, 0, stream>>>(
        f3, h3, window, rw3, acc, B, 64, 0.125f / (8.f * 64.f * 64.f));

    finalize_kernel<<<1, 64, 0, stream>>>(acc, out);
}

// Round 3
// 73.770 us; speedup vs baseline: 2.4696x; 1.1652x over previous
//
#include <hip/hip_runtime.h>
#include <hip/hip_bf16.h>

// Fused per-level kernel: bilateral-window MSE partial loss for level k
// (+ optional bicubic /2 downsample of fake/hdr to level k+1, reusing the
// LDS halo tile). Block partials go to unique double slots (no atomics,
// no zero-init needed). PX = pixels per thread along x (float2 rw loads).
template <int PX, bool WD>
__global__ __launch_bounds__(256) void loss_kernel(
    const float* __restrict__ F0, const float* __restrict__ H0,
    const float* __restrict__ window, const float* __restrict__ rw,
    double* __restrict__ slots, int S, float scale,
    float* __restrict__ fdown, float* __restrict__ hdown)
{
    constexpr int TW = PX * 64;       // tile width (pixels)
    __shared__ float sf[8][TW + 4];   // 4 rows + 2x2 halo
    __shared__ float sh[8][TW + 4];
    __shared__ float swin[25];
    __shared__ float wred[4];

    const int tx = threadIdx.x, ty = threadIdx.y;
    const int tid = ty * 64 + tx;
    if (tid < 25) swin[tid] = window[tid];

    const int bx0 = blockIdx.x * TW, by0 = blockIdx.y * 4, b = blockIdx.z;
    const float* F  = F0 + (size_t)b * S * S;
    const float* Hp = H0 + (size_t)b * S * S;

    // halo tile load, zero-padded outside image (matches jnp.pad constant-0)
    for (int i = tid; i < 8 * (TW + 4); i += 256) {
        const int r = i / (TW + 4), c = i % (TW + 4);
        const int y = by0 + r - 2, x = bx0 + c - 2;
        float fv = 0.f, hv = 0.f;
        if ((unsigned)y < (unsigned)S && (unsigned)x < (unsigned)S) {
            const size_t id = (size_t)y * S + x;
            fv = F[id]; hv = Hp[id];
        }
        sf[r][c] = fv; sh[r][c] = hv;
    }
    __syncthreads();

    const int x0 = bx0 + PX * tx, y = by0 + ty;
    const size_t ks = (size_t)S * S;
    const float* rwp = rw + (size_t)b * 25 * ks + (size_t)y * S + x0;

    float wsum[PX], fs[PX], hs[PX];
#pragma unroll
    for (int p = 0; p < PX; ++p) { wsum[p] = 0.f; fs[p] = 0.f; hs[p] = 0.f; }

#pragma unroll
    for (int di = 0; di < 5; ++di) {
        float f6[PX + 4], h6[PX + 4];
        if constexpr (PX == 2) {
            const float2* pf = (const float2*)&sf[ty + di][2 * tx];
            const float2* ph = (const float2*)&sh[ty + di][2 * tx];
            float2 a = pf[0], bb = pf[1], cc = pf[2];
            f6[0] = a.x; f6[1] = a.y; f6[2] = bb.x; f6[3] = bb.y; f6[4] = cc.x; f6[5] = cc.y;
            float2 d = ph[0], e = ph[1], g = ph[2];
            h6[0] = d.x; h6[1] = d.y; h6[2] = e.x; h6[3] = e.y; h6[4] = g.x; h6[5] = g.y;
        } else {
#pragma unroll
            for (int j = 0; j < 5; ++j) {
                f6[j] = sf[ty + di][tx + j];
                h6[j] = sh[ty + di][tx + j];
            }
        }
#pragma unroll
        for (int dj = 0; dj < 5; ++dj) {
            const int k = di * 5 + dj;
            float rv[PX];
            if constexpr (PX == 2) {
                const float2 t = *(const float2*)(rwp + (size_t)k * ks);
                rv[0] = t.x; rv[1] = t.y;
            } else {
                rv[0] = rwp[(size_t)k * ks];
            }
#pragma unroll
            for (int p = 0; p < PX; ++p) {
                const float wm = swin[k] * rv[p];
                wsum[p] += wm;
                fs[p] = fmaf(wm, f6[dj + p], fs[p]);
                hs[p] = fmaf(wm, h6[dj + p], hs[p]);
            }
        }
    }
    float v = 0.f;
#pragma unroll
    for (int p = 0; p < PX; ++p) {
        const float d = (fs[p] - hs[p]) / wsum[p];
        v = fmaf(d, d, v);
    }

    // block reduction: wave shuffle -> LDS; down2 work fills the barrier slack
#pragma unroll
    for (int off = 32; off > 0; off >>= 1) v += __shfl_down(v, off, 64);
    if ((tid & 63) == 0) wred[tid >> 6] = v;

    if constexpr (WD) {
        // bicubic /2 (taps at src 2i-1..2i+2, edge-clamped) from the LDS tile.
        // 2 output rows x PX*32 cols per image; clamped coords always fall
        // inside the halo tile, and clamping avoids the zero-pad entries.
        const int Sh = S >> 1;
        if (tid < 128 * PX) {
            const int img = tid >= 64 * PX;
            const int t2 = tid & (64 * PX - 1);
            const int r = t2 / (PX * 32), c = t2 % (PX * 32);
            const int y1 = (by0 >> 1) + r, x1 = (bx0 >> 1) + c;
            const float wt[4] = {-0.09375f, 0.59375f, 0.59375f, -0.09375f};
            float (*s)[TW + 4] = img ? sh : sf;
            int lc[4];
#pragma unroll
            for (int kx = 0; kx < 4; ++kx) {
                int gx = bx0 + 2 * c - 1 + kx;
                lc[kx] = min(max(gx, 0), S - 1) - bx0 + 2;
            }
            float acc = 0.f;
#pragma unroll
            for (int ky = 0; ky < 4; ++ky) {
                int gy = by0 + 2 * r - 1 + ky;
                const int lr = min(max(gy, 0), S - 1) - by0 + 2;
                const float rs = wt[0] * (s[lr][lc[0]] + s[lr][lc[3]])
                               + wt[1] * (s[lr][lc[1]] + s[lr][lc[2]]);
                acc = fmaf(wt[ky], rs, acc);
            }
            float* dst = img ? hdown : fdown;
            dst[((size_t)b * Sh + y1) * Sh + x1] = acc;
        }
    }

    __syncthreads();
    if (tid == 0) {
        const float sB = wred[0] + wred[1] + wred[2] + wred[3];
        const unsigned lin = blockIdx.x + gridDim.x * (blockIdx.y + gridDim.y * blockIdx.z);
        slots[lin] = (double)sB * (double)scale;
    }
}

__global__ void finalize_kernel(const double* __restrict__ slots, float* __restrict__ out, int n)
{
    __shared__ double wred[4];
    const int t = threadIdx.x;  // 256 threads
    double s = 0.0;
    for (int i = t; i < n; i += 256) s += slots[i];
#pragma unroll
    for (int off = 32; off > 0; off >>= 1) s += __shfl_down(s, off, 64);
    if ((t & 63) == 0) wred[t >> 6] = s;
    __syncthreads();
    if (t == 0) out[0] = (float)(wred[0] + wred[1] + wred[2] + wred[3]);
}

extern "C" void kernel_launch(void* const* d_in, const int* in_sizes, int n_in,
                              void* d_out, int out_size, void* d_ws, size_t ws_size,
                              hipStream_t stream)
{
    const float* fake   = (const float*)d_in[0];
    const float* hdr    = (const float*)d_in[1];
    const float* window = (const float*)d_in[2];
    const float* rw0    = (const float*)d_in[3];
    const float* rw1    = (const float*)d_in[4];
    const float* rw2    = (const float*)d_in[5];
    const float* rw3    = (const float*)d_in[6];
    float* out = (float*)d_out;

    const int B = 8;
    char* ws = (char*)d_ws;
    double* slots = (double*)ws;                 // 5504 doubles, all stored each call
    float* f1 = (float*)(ws + 65536);
    const size_t n1 = (size_t)B * 256 * 256;
    float* h1 = f1 + n1;
    float* f2 = h1 + n1;
    const size_t n2 = (size_t)B * 128 * 128;
    float* h2 = f2 + n2;
    float* f3 = h2 + n2;
    const size_t n3 = (size_t)B * 64 * 64;
    float* h3 = f3 + n3;

    const dim3 blk(64, 4);

    // level 0: loss + produce 256^2 pyramid          4096 blocks
    loss_kernel<2, true><<<dim3(4, 128, B), blk, 0, stream>>>(
        fake, hdr, window, rw0, slots, 512, 1.0f / (8.f * 512.f * 512.f), f1, h1);
    // level 1: loss + produce 128^2 pyramid          1024 blocks
    loss_kernel<2, true><<<dim3(2, 64, B), blk, 0, stream>>>(
        f1, h1, window, rw1, slots + 4096, 256, 0.5f / (8.f * 256.f * 256.f), f2, h2);
    // level 2: loss + produce 64^2 pyramid            256 blocks
    loss_kernel<2, true><<<dim3(1, 32, B), blk, 0, stream>>>(
        f2, h2, window, rw2, slots + 5120, 128, 0.25f / (8.f * 128.f * 128.f), f3, h3);
    // level 3: loss only                              128 blocks
    loss_kernel<1, false><<<dim3(1, 16, B), blk, 0, stream>>>(
        f3, h3, window, rw3, slots + 5376, 64, 0.125f / (8.f * 64.f * 64.f),
        nullptr, nullptr);

    finalize_kernel<<<1, 256, 0, stream>>>(slots, out, 5504);
}